// Round 2
// baseline (628.040 us; speedup 1.0000x reference)
//
#include <hip/hip_runtime.h>
#include <cmath>

#define HH 512
#define WW 512
#define NIMG 64
#define OHH 502
#define OWW 502

struct KTaps {
    float kw[11];   // normalized gaussian, win=11, sigma=1.5
    float ke[13];   // erf-gaussian, 13 taps, NOT normalized
};

// ---------------- Kernel A: SSIM map -> scalar sum ----------------
// Tile: 32 wide x 16 tall outputs. LDS 25.8 KB -> 6 blocks/CU (75% occ).
__global__ __launch_bounds__(256, 6) void ssim_reduce_kernel(
        const float* __restrict__ x, const float* __restrict__ y,
        double* __restrict__ ssum, KTaps kt) {
    __shared__ float sx[26][44];      // rows bi..bi+25, cols bj..bj+41 (42 used)
    __shared__ float sy[26][44];      // stride 44 keeps float4 alignment per row
    __shared__ float h[5][26][32];    // hx,hy,hxx,hyy,hxy after horizontal pass

    const int n  = blockIdx.z;
    const int bi = blockIdx.y * 16;
    const int bj = blockIdx.x * 32;
    const int tid = threadIdx.x;

    const float* __restrict__ xi = x + (size_t)n * HH * WW;
    const float* __restrict__ yi = y + (size_t)n * HH * WW;

    // load 26x42 halo (bounds-checked; OOB zeros feed masked outputs only)
    for (int idx = tid; idx < 26 * 42; idx += 256) {
        const int r = idx / 42, c = idx - r * 42;
        const int gr = bi + r, gc = bj + c;
        float xv = 0.f, yv = 0.f;
        if (gr < HH && gc < WW) { xv = xi[gr * WW + gc]; yv = yi[gr * WW + gc]; }
        sx[r][c] = xv;
        sy[r][c] = yv;
    }
    __syncthreads();

    // horizontal pass: each active thread does 4 consecutive output cols of one row.
    // 26 rows x 8 col-groups = 208 units. 16 values via 4x ds_read_b128 cover all
    // four 11-tap windows.
    if (tid < 208) {
        const int r = tid >> 3, c0 = (tid & 7) * 4;
        float xv[16], yv[16];
        const float4* px = (const float4*)&sx[r][c0];
        const float4* py = (const float4*)&sy[r][c0];
#pragma unroll
        for (int q = 0; q < 4; ++q) {
            const float4 a = px[q], b = py[q];
            xv[q*4+0]=a.x; xv[q*4+1]=a.y; xv[q*4+2]=a.z; xv[q*4+3]=a.w;
            yv[q*4+0]=b.x; yv[q*4+1]=b.y; yv[q*4+2]=b.z; yv[q*4+3]=b.w;
        }
        float ax[4], ay[4], axx[4], ayy[4], axy[4];
#pragma unroll
        for (int k = 0; k < 4; ++k) { ax[k]=0.f; ay[k]=0.f; axx[k]=0.f; ayy[k]=0.f; axy[k]=0.f; }
#pragma unroll
        for (int v = 0; v < 11; ++v) {
            const float w = kt.kw[v];
#pragma unroll
            for (int k = 0; k < 4; ++k) {
                const float xx = xv[k + v], yy = yv[k + v];
                ax[k]  += w * xx;
                ay[k]  += w * yy;
                axx[k] += w * xx * xx;
                ayy[k] += w * yy * yy;
                axy[k] += w * xx * yy;
            }
        }
        *(float4*)&h[0][r][c0] = make_float4(ax[0], ax[1], ax[2], ax[3]);
        *(float4*)&h[1][r][c0] = make_float4(ay[0], ay[1], ay[2], ay[3]);
        *(float4*)&h[2][r][c0] = make_float4(axx[0], axx[1], axx[2], axx[3]);
        *(float4*)&h[3][r][c0] = make_float4(ayy[0], ayy[1], ayy[2], ayy[3]);
        *(float4*)&h[4][r][c0] = make_float4(axy[0], axy[1], axy[2], axy[3]);
    }
    __syncthreads();

    const float c1 = 1e-4f;
    const float c2 = 9e-4f;
    float acc = 0.f;

    // vertical pass: each thread does 2 consecutive output rows of one column.
    // 32 cols x 8 row-groups = 256 units. 12 loads/quantity cover both 11-tap windows.
    {
        const int c = tid & 31;
        const int r0 = (tid >> 5) * 2;
        float m0[5], m1[5];
#pragma unroll
        for (int q = 0; q < 5; ++q) {
            float v[12];
#pragma unroll
            for (int u = 0; u < 12; ++u) v[u] = h[q][r0 + u][c];
            float s0 = 0.f, s1 = 0.f;
#pragma unroll
            for (int u = 0; u < 11; ++u) {
                const float w = kt.kw[u];
                s0 += w * v[u];
                s1 += w * v[u + 1];
            }
            m0[q] = s0; m1[q] = s1;
        }
        const int go_j = bj + c;
#pragma unroll
        for (int t = 0; t < 2; ++t) {
            const int go_i = bi + r0 + t;
            if (go_i < OHH && go_j < OWW) {
                const float mx  = t ? m1[0] : m0[0];
                const float my  = t ? m1[1] : m0[1];
                const float mxx = t ? m1[2] : m0[2];
                const float myy = t ? m1[3] : m0[3];
                const float mxy = t ? m1[4] : m0[4];
                const float vx  = mxx - mx * mx;
                const float vy  = myy - my * my;
                const float cov = mxy - mx * my;
                acc += ((2.f * mx * my + c1) * (2.f * cov + c2)) /
                       ((mx * mx + my * my + c1) * (vx + vy + c2));
            }
        }
    }

    // wave shuffle reduce -> cross-wave LDS -> one atomic/block
#pragma unroll
    for (int off = 32; off > 0; off >>= 1)
        acc += __shfl_down(acc, off, 64);
    __shared__ float wsum[4];
    const int wid = tid >> 6, lane = tid & 63;
    if (lane == 0) wsum[wid] = acc;
    __syncthreads();
    if (tid == 0) {
        const float s = wsum[0] + wsum[1] + wsum[2] + wsum[3];
        atomicAdd(ssum, (double)s);
    }
}

// ---------------- Kernel B: L1 map + combine with ssim scalar ----------------
// Tile: 32x32 outputs. LDS ~14 KB (waves-capped occupancy).
__global__ __launch_bounds__(256) void l1_combine_kernel(
        const float* __restrict__ x, const float* __restrict__ y,
        const double* __restrict__ ssum, float* __restrict__ out, KTaps kt) {
    __shared__ float sd[44][48];   // d = y - x halo, stride 48 for alignment
    __shared__ float hd[44][32];

    const int n  = blockIdx.z;
    const int bi = blockIdx.y * 32;
    const int bj = blockIdx.x * 32;
    const int tid = threadIdx.x;

    const float* __restrict__ xi = x + (size_t)n * HH * WW;
    const float* __restrict__ yi = y + (size_t)n * HH * WW;

    // load 44x44 halo of d = y - x with zero padding (SAME conv, pad=6)
    for (int idx = tid; idx < 44 * 44; idx += 256) {
        const int r = idx / 44, c = idx - r * 44;
        const int gr = bi + r - 6, gc = bj + c - 6;
        float v = 0.f;
        if (gr >= 0 && gr < HH && gc >= 0 && gc < WW)
            v = yi[gr * WW + gc] - xi[gr * WW + gc];
        sd[r][c] = v;
    }
    __syncthreads();

    // horizontal 13-tap pass: 4 output cols/thread, 44 rows x 8 groups = 352 units.
    for (int idx = tid; idx < 352; idx += 256) {
        const int r = idx >> 3, c0 = (idx & 7) * 4;
        float dv[16];
        const float4* pd = (const float4*)&sd[r][c0];
#pragma unroll
        for (int q = 0; q < 4; ++q) {
            const float4 a = pd[q];
            dv[q*4+0]=a.x; dv[q*4+1]=a.y; dv[q*4+2]=a.z; dv[q*4+3]=a.w;
        }
        float a0 = 0.f, a1 = 0.f, a2 = 0.f, a3 = 0.f;
#pragma unroll
        for (int v = 0; v < 13; ++v) {
            const float w = kt.ke[v];
            a0 += w * dv[v];
            a1 += w * dv[v + 1];
            a2 += w * dv[v + 2];
            a3 += w * dv[v + 3];
        }
        *(float4*)&hd[r][c0] = make_float4(a0, a1, a2, a3);
    }
    __syncthreads();

    const float inv_cnt = 1.f / 16128256.f;   // 64*502*502
    const float ssim_loss = 1.f - (float)(*ssum) * inv_cnt;
    const float base = 100.f * 0.84f * ssim_loss;

    // vertical 13-tap pass: 4 output rows/thread. 32 cols x 8 groups = 256 units.
    float* __restrict__ oi = out + (size_t)n * HH * WW;
    {
        const int c = tid & 31;
        const int r0 = (tid >> 5) * 4;
        float v[16];
#pragma unroll
        for (int u = 0; u < 16; ++u) v[u] = hd[r0 + u][c];
#pragma unroll
        for (int t = 0; t < 4; ++t) {
            float a = 0.f;
#pragma unroll
            for (int u = 0; u < 13; ++u) a += kt.ke[u] * v[t + u];
            oi[(size_t)(bi + r0 + t) * WW + (bj + c)] = base + 100.f * 0.16f * fabsf(a);
        }
    }
}

extern "C" void kernel_launch(void* const* d_in, const int* in_sizes, int n_in,
                              void* d_out, int out_size, void* d_ws, size_t ws_size,
                              hipStream_t stream) {
    const float* x = (const float*)d_in[0];
    const float* y = (const float*)d_in[1];
    float* out = (float*)d_out;
    double* ssum = (double*)d_ws;

    KTaps kt;
    {   // normalized gaussian win=11 sigma=1.5 (exp-based)
        double g[11], s = 0.0;
        for (int i = 0; i < 11; ++i) {
            const double d = (double)i - 5.0;
            g[i] = std::exp(-(d * d) / 4.5);
            s += g[i];
        }
        for (int i = 0; i < 11; ++i) kt.kw[i] = (float)(g[i] / s);
    }
    {   // erf-gaussian, tail=6 -> 13 taps, sigma=1.5, NOT normalized
        const double t = 0.70710678 / 1.5;
        for (int i = 0; i < 13; ++i) {
            const double xx = (double)i - 6.0;
            const double v = 0.5 * (std::erf(t * (xx + 0.5)) - std::erf(t * (xx - 0.5)));
            kt.ke[i] = (float)(v < 0.0 ? 0.0 : v);
        }
    }

    hipMemsetAsync(ssum, 0, sizeof(double), stream);

    dim3 blk(256);
    dim3 grdA((OWW + 31) / 32, (OHH + 15) / 16, NIMG);   // 16 x 32 x 64
    ssim_reduce_kernel<<<grdA, blk, 0, stream>>>(x, y, ssum, kt);

    dim3 grdB(WW / 32, HH / 32, NIMG);                   // 16 x 16 x 64
    l1_combine_kernel<<<grdB, blk, 0, stream>>>(x, y, ssum, out, kt);
}

// Round 3
// 353.089 us; speedup vs baseline: 1.7787x; 1.7787x over previous
//
#include <hip/hip_runtime.h>
#include <cmath>

#define IMG_W 512
#define IMG_H 512
#define NIMG 64
#define OWV 502            // valid-conv output extent (SSIM branch)
#define STRIP 256
#define BANDROWS 64

struct KTaps {
    float kw[11];   // normalized gaussian, win=11, sigma=1.5 (SSIM)
    float ke[13];   // erf-gaussian, 13 taps, NOT normalized (L1)
};

// ---------------- Kernel A: SSIM -> scalar sum ----------------
// Persistent band: block owns 256-col strip x 64-output-row band, marches 74
// input rows. Vertical filter lives in 11x5 pending register accumulators
// (phase-unrolled mod 11) -> zero LDS traffic for the v-pass.
__global__ __launch_bounds__(256) void ssim_band_kernel(
        const float* __restrict__ x, const float* __restrict__ y,
        double* __restrict__ ssum, KTaps kt) {
    __shared__ __align__(16) float sx[2][272];
    __shared__ __align__(16) float sy[2][272];
    __shared__ __align__(16) float hbuf[2][5][STRIP];

    const int img   = blockIdx.z;
    const int band  = blockIdx.y;       // 0..7
    const int strip = blockIdx.x;       // 0..1
    const int tid   = threadIdx.x;
    const int r0    = band * BANDROWS;  // first input row of band
    const int c0    = strip * STRIP;

    const float* __restrict__ xi = x + (size_t)img * IMG_H * IMG_W;
    const float* __restrict__ yi = y + (size_t)img * IMG_H * IMG_W;

    float acc[11][5];
#pragma unroll
    for (int i = 0; i < 11; ++i)
#pragma unroll
        for (int q = 0; q < 5; ++q) acc[i][q] = 0.f;
    float tsum = 0.f;

    const int t2 = tid - 128;

    // stage input row rr into x/y row buffer b (called by threads 128..255)
    auto stage = [&](int rr, int b) {
        const int r = r0 + rr;
        const bool rowok = (r < IMG_H);
        if (t2 >= 0 && t2 < 67) {                 // 67 float4 = 268 cols of x
            const int g = c0 + 4 * t2;
            float4 v = make_float4(0.f, 0.f, 0.f, 0.f);
            if (rowok && g + 3 < IMG_W) v = *(const float4*)(xi + (size_t)r * IMG_W + g);
            *(float4*)&sx[b][4 * t2] = v;
        }
        if (t2 >= 61) {                           // 67 float4 of y
            const int t3 = t2 - 61;
            const int g = c0 + 4 * t3;
            float4 v = make_float4(0.f, 0.f, 0.f, 0.f);
            if (rowok && g + 3 < IMG_W) v = *(const float4*)(yi + (size_t)r * IMG_W + g);
            *(float4*)&sy[b][4 * t3] = v;
        }
    };

    if (t2 >= 0) stage(0, 0);
    __syncthreads();

    for (int chunk = 0; chunk < 7; ++chunk) {
#pragma unroll
        for (int p = 0; p < 11; ++p) {
            const int rr = chunk * 11 + p;        // block-uniform
            if (rr <= 73) {
                const int b = rr & 1;
                if (tid >= 128) {
                    if (rr < 73) stage(rr + 1, b ^ 1);
                } else {
                    // h-pass: thread t filters local cols 2t, 2t+1 (b64-aligned window)
                    const int t = tid;
                    float xw[12], yw[12];
#pragma unroll
                    for (int j = 0; j < 6; ++j) {
                        const float2 a = *(const float2*)&sx[b][2 * t + 2 * j];
                        const float2 c = *(const float2*)&sy[b][2 * t + 2 * j];
                        xw[2 * j] = a.x; xw[2 * j + 1] = a.y;
                        yw[2 * j] = c.x; yw[2 * j + 1] = c.y;
                    }
                    float ha0 = 0.f, ha1 = 0.f, ha2 = 0.f, ha3 = 0.f, ha4 = 0.f;
                    float hb0 = 0.f, hb1 = 0.f, hb2 = 0.f, hb3 = 0.f, hb4 = 0.f;
#pragma unroll
                    for (int j = 0; j < 12; ++j) {
                        const float xv = xw[j], yv = yw[j];
                        const float xx = xv * xv, yy = yv * yv, xy = xv * yv;
                        if (j < 11) {
                            const float w = kt.kw[j];
                            ha0 += w * xv; ha1 += w * yv; ha2 += w * xx;
                            ha3 += w * yy; ha4 += w * xy;
                        }
                        if (j >= 1) {
                            const float w = kt.kw[j - 1];
                            hb0 += w * xv; hb1 += w * yv; hb2 += w * xx;
                            hb3 += w * yy; hb4 += w * xy;
                        }
                    }
                    *(float2*)&hbuf[b][0][2 * t] = make_float2(ha0, hb0);
                    *(float2*)&hbuf[b][1][2 * t] = make_float2(ha1, hb1);
                    *(float2*)&hbuf[b][2][2 * t] = make_float2(ha2, hb2);
                    *(float2*)&hbuf[b][3][2 * t] = make_float2(ha3, hb3);
                    *(float2*)&hbuf[b][4][2 * t] = make_float2(ha4, hb4);
                }
                __syncthreads();

                // v-pass: all threads, col = c0+tid; 55 FMAs into pending slots
                const float hv0 = hbuf[b][0][tid];
                const float hv1 = hbuf[b][1][tid];
                const float hv2 = hbuf[b][2][tid];
                const float hv3 = hbuf[b][3][tid];
                const float hv4 = hbuf[b][4][tid];
#pragma unroll
                for (int d = 0; d <= 10; ++d) {
                    const int s = (p + 11 - d) % 11;   // compile-time constant
                    const float w = kt.kw[d];
                    acc[s][0] += w * hv0; acc[s][1] += w * hv1; acc[s][2] += w * hv2;
                    acc[s][3] += w * hv3; acc[s][4] += w * hv4;
                }
                {   // slot (p+1)%11 completed output row ro = rr-10
                    const int sc = (p + 1) % 11;
                    const int ro = rr - 10;
                    if (ro >= 0) {
                        const int o = r0 + ro;
                        const int c = c0 + tid;
                        if (o < OWV && c < OWV) {
                            const float mx = acc[sc][0], my = acc[sc][1];
                            const float mxx = acc[sc][2], myy = acc[sc][3], mxy = acc[sc][4];
                            const float vx = mxx - mx * mx, vy = myy - my * my;
                            const float cov = mxy - mx * my;
                            const float c1 = 1e-4f, c2 = 9e-4f;
                            tsum += ((2.f * mx * my + c1) * (2.f * cov + c2)) /
                                    ((mx * mx + my * my + c1) * (vx + vy + c2));
                        }
                    }
                    // ALWAYS reset: slot becomes output row rr+1's accumulator
#pragma unroll
                    for (int q = 0; q < 5; ++q) acc[sc][q] = 0.f;
                }
            }
        }
    }

    // reduce + one atomic per block (1024 blocks total)
#pragma unroll
    for (int off = 32; off > 0; off >>= 1) tsum += __shfl_down(tsum, off, 64);
    __shared__ float wsum[4];
    const int wid = tid >> 6, lane = tid & 63;
    if (lane == 0) wsum[wid] = tsum;
    __syncthreads();
    if (tid == 0) atomicAdd(ssum, (double)(wsum[0] + wsum[1] + wsum[2] + wsum[3]));
}

// ---------------- Kernel B: L1 map + combine ----------------
// Same skeleton: 13-tap SAME conv of d = y-x, 13 pending register slots.
__global__ __launch_bounds__(256) void l1_band_kernel(
        const float* __restrict__ x, const float* __restrict__ y,
        const double* __restrict__ ssum, float* __restrict__ out, KTaps kt) {
    __shared__ __align__(16) float sd[2][280];   // 272 staged: cols c0-8 .. c0+263
    __shared__ __align__(16) float hb[2][STRIP];

    const int img   = blockIdx.z;
    const int band  = blockIdx.y;
    const int strip = blockIdx.x;
    const int tid   = threadIdx.x;
    const int o0    = band * BANDROWS;   // first output row
    const int rin0  = o0 - 6;            // first input row (SAME pad=6)
    const int c0    = strip * STRIP;

    const float* __restrict__ xi = x + (size_t)img * IMG_H * IMG_W;
    const float* __restrict__ yi = y + (size_t)img * IMG_H * IMG_W;
    float* __restrict__ oi = out + (size_t)img * IMG_H * IMG_W;

    const float base = 100.f * 0.84f * (1.f - (float)(*ssum) * (1.f / 16128256.f));

    float acc[13];
#pragma unroll
    for (int i = 0; i < 13; ++i) acc[i] = 0.f;

    const int t2 = tid - 128;
    auto stage = [&](int rr, int b) {
        if (t2 >= 0 && t2 < 68) {        // 68 float4 = 272 cols of d = y-x
            const int r = rin0 + rr;
            const int g = c0 - 8 + 4 * t2;     // 16B-aligned; f4 fully in or out
            float4 v = make_float4(0.f, 0.f, 0.f, 0.f);
            if (r >= 0 && r < IMG_H && g >= 0 && g + 3 < IMG_W) {
                const float4 a = *(const float4*)(xi + (size_t)r * IMG_W + g);
                const float4 bb = *(const float4*)(yi + (size_t)r * IMG_W + g);
                v = make_float4(bb.x - a.x, bb.y - a.y, bb.z - a.z, bb.w - a.w);
            }
            *(float4*)&sd[b][4 * t2] = v;
        }
    };

    if (t2 >= 0) stage(0, 0);
    __syncthreads();

    for (int chunk = 0; chunk < 6; ++chunk) {
#pragma unroll
        for (int p = 0; p < 13; ++p) {
            const int rr = chunk * 13 + p;       // block-uniform, 0..75 used
            if (rr <= 75) {
                const int b = rr & 1;
                if (tid >= 128) {
                    if (rr < 75) stage(rr + 1, b ^ 1);
                } else {
                    // h-pass: cols 2t, 2t+1; window idx 2t+2 .. 2t+15 (b64-aligned)
                    const int t = tid;
                    float dw[14];
#pragma unroll
                    for (int j = 0; j < 7; ++j) {
                        const float2 a = *(const float2*)&sd[b][2 * t + 2 + 2 * j];
                        dw[2 * j] = a.x; dw[2 * j + 1] = a.y;
                    }
                    float h0 = 0.f, h1 = 0.f;
#pragma unroll
                    for (int u = 0; u < 13; ++u) {
                        h0 += kt.ke[u] * dw[u];
                        h1 += kt.ke[u] * dw[u + 1];
                    }
                    *(float2*)&hb[b][2 * t] = make_float2(h0, h1);
                }
                __syncthreads();

                const float hv = hb[b][tid];
#pragma unroll
                for (int dd = 0; dd <= 12; ++dd) {
                    const int s = (p + 13 - dd) % 13;
                    acc[s] += kt.ke[dd] * hv;
                }
                {
                    const int sc = (p + 1) % 13;
                    const int ro = rr - 12;           // completed output row
                    if (ro >= 0) {
                        const int o = o0 + ro;        // always < 512
                        oi[(size_t)o * IMG_W + (c0 + tid)] = base + 16.f * fabsf(acc[sc]);
                    }
                    acc[sc] = 0.f;                    // ALWAYS reset
                }
            }
        }
    }
}

extern "C" void kernel_launch(void* const* d_in, const int* in_sizes, int n_in,
                              void* d_out, int out_size, void* d_ws, size_t ws_size,
                              hipStream_t stream) {
    const float* x = (const float*)d_in[0];
    const float* y = (const float*)d_in[1];
    float* out = (float*)d_out;
    double* ssum = (double*)d_ws;

    KTaps kt;
    {   // normalized gaussian win=11 sigma=1.5 (exp-based)
        double g[11], s = 0.0;
        for (int i = 0; i < 11; ++i) {
            const double d = (double)i - 5.0;
            g[i] = std::exp(-(d * d) / 4.5);
            s += g[i];
        }
        for (int i = 0; i < 11; ++i) kt.kw[i] = (float)(g[i] / s);
    }
    {   // erf-gaussian, tail=6 -> 13 taps, sigma=1.5, NOT normalized
        const double t = 0.70710678 / 1.5;
        for (int i = 0; i < 13; ++i) {
            const double xx = (double)i - 6.0;
            const double v = 0.5 * (std::erf(t * (xx + 0.5)) - std::erf(t * (xx - 0.5)));
            kt.ke[i] = (float)(v < 0.0 ? 0.0 : v);
        }
    }

    hipMemsetAsync(ssum, 0, sizeof(double), stream);

    dim3 blk(256);
    dim3 grd(2, 8, NIMG);   // strips x bands x images = 1024 blocks (4/CU)
    ssim_band_kernel<<<grd, blk, 0, stream>>>(x, y, ssum, kt);
    l1_band_kernel<<<grd, blk, 0, stream>>>(x, y, ssum, out, kt);
}

// Round 4
// 302.085 us; speedup vs baseline: 2.0790x; 1.1688x over previous
//
#include <hip/hip_runtime.h>
#include <cmath>

#define IMG_W 512
#define IMG_H 512
#define NIMG 64
#define OWV 502   // valid-conv output extent (SSIM branch)

struct KTaps {
    float kw[11];   // normalized gaussian, win=11, sigma=1.5 (SSIM)
    float ke[13];   // erf-gaussian, 13 taps, NOT normalized (L1)
};

// ---------------- Kernel A: SSIM -> scalar sum ----------------
// Block owns a 256-col strip x 64-output-row band. Per input row (74 iters):
// all threads prefetch next row to regs, fused h-pass (per-thread 12-value
// window, parity-resolved weights) feeds mod-11 pending v-accumulators in
// registers. One barrier per row. No hbuf, no producer/consumer split.
__global__ __launch_bounds__(256) void ssim_band_kernel(
        const float* __restrict__ x, const float* __restrict__ y,
        double* __restrict__ ssum, KTaps kt) {
    __shared__ __align__(16) float sx[2][272];   // staged cols c0..c0+265
    __shared__ __align__(16) float sy[2][272];

    const int img   = blockIdx.z;
    const int band  = blockIdx.y;     // 0..7
    const int strip = blockIdx.x;     // 0..1
    const int tid   = threadIdx.x;
    const int r0    = band * 64;
    const int c0    = strip * 256;

    const float* __restrict__ xi = x + (size_t)img * IMG_H * IMG_W;
    const float* __restrict__ yi = y + (size_t)img * IMG_H * IMG_W;

    // parity-resolved 12-tap weights: window read is f2-aligned from even base;
    // even cols use taps [0..10], odd cols taps shifted by one. Static indexing.
    float w12[12];
#pragma unroll
    for (int j = 0; j < 12; ++j) w12[j] = 0.f;
    if (tid & 1) {
#pragma unroll
        for (int j = 0; j < 11; ++j) w12[j + 1] = kt.kw[j];
    } else {
#pragma unroll
        for (int j = 0; j < 11; ++j) w12[j] = kt.kw[j];
    }

    float acc[11][5];
#pragma unroll
    for (int i = 0; i < 11; ++i)
#pragma unroll
        for (int q = 0; q < 5; ++q) acc[i][q] = 0.f;
    float tsum = 0.f;

    const int basei = tid & ~1;      // even LDS base of this thread's window
    const int outc  = c0 + tid;

    auto ldx = [&](int r, int g) -> float2 {   // g even; zero OOB
        float2 v = make_float2(0.f, 0.f);
        if (r < IMG_H && g < IMG_W) v = *(const float2*)(xi + (size_t)r * IMG_W + g);
        return v;
    };
    auto ldy = [&](int r, int g) -> float2 {
        float2 v = make_float2(0.f, 0.f);
        if (r < IMG_H && g < IMG_W) v = *(const float2*)(yi + (size_t)r * IMG_W + g);
        return v;
    };

    // stage row r0 -> buf 0 (133 f2 per array; threads 123..132 do both)
    if (tid < 133) { float2 v = ldx(r0, c0 + 2 * tid); *(float2*)&sx[0][2 * tid] = v; }
    if (tid >= 123) { const int t3 = tid - 123; float2 v = ldy(r0, c0 + 2 * t3); *(float2*)&sy[0][2 * t3] = v; }
    __syncthreads();

#pragma unroll 1
    for (int chunk = 0; chunk < 7; ++chunk) {
#pragma unroll
        for (int p = 0; p < 11; ++p) {
            const int rr = chunk * 11 + p;
            if (rr <= 73) {
                const int b = rr & 1;
                // prefetch next row into regs (hidden under this row's compute)
                float2 px = make_float2(0.f, 0.f), py = make_float2(0.f, 0.f);
                const bool pre = (rr < 73);
                if (pre) {
                    if (tid < 133) px = ldx(r0 + rr + 1, c0 + 2 * tid);
                    if (tid >= 123) py = ldy(r0 + rr + 1, c0 + 2 * (tid - 123));
                }
                // fused h-pass: 12-value window, 5 quantities
                float xv[12], yv[12];
#pragma unroll
                for (int j = 0; j < 6; ++j) {
                    const float2 a = *(const float2*)&sx[b][basei + 2 * j];
                    const float2 c = *(const float2*)&sy[b][basei + 2 * j];
                    xv[2 * j] = a.x; xv[2 * j + 1] = a.y;
                    yv[2 * j] = c.x; yv[2 * j + 1] = c.y;
                }
                float h0 = 0.f, h1 = 0.f, h2 = 0.f, h3 = 0.f, h4 = 0.f;
#pragma unroll
                for (int j = 0; j < 12; ++j) {
                    const float w = w12[j];
                    const float a = xv[j], bb = yv[j];
                    h0 += w * a;
                    h1 += w * bb;
                    h2 += w * (a * a);
                    h3 += w * (bb * bb);
                    h4 += w * (a * bb);
                }
                // v-pass: 55 FMAs into mod-11 pending slots (static indices)
#pragma unroll
                for (int d = 0; d <= 10; ++d) {
                    const int s = (p + 11 - d) % 11;
                    const float w = kt.kw[d];
                    acc[s][0] += w * h0; acc[s][1] += w * h1; acc[s][2] += w * h2;
                    acc[s][3] += w * h3; acc[s][4] += w * h4;
                }
                {   // slot (p+1)%11 completed output row ro = rr-10
                    const int sc = (p + 1) % 11;
                    const int ro = rr - 10;
                    if (ro >= 0) {
                        const int o = r0 + ro;
                        if (o < OWV && outc < OWV) {
                            const float mx = acc[sc][0], my = acc[sc][1];
                            const float vx = acc[sc][2] - mx * mx;
                            const float vy = acc[sc][3] - my * my;
                            const float cov = acc[sc][4] - mx * my;
                            const float c1 = 1e-4f, c2 = 9e-4f;
                            tsum += ((2.f * mx * my + c1) * (2.f * cov + c2)) /
                                    ((mx * mx + my * my + c1) * (vx + vy + c2));
                        }
                    }
#pragma unroll
                    for (int q = 0; q < 5; ++q) acc[sc][q] = 0.f;   // ALWAYS reset
                }
                // write prefetched row to the other buffer
                if (pre) {
                    const int bn = b ^ 1;
                    if (tid < 133) *(float2*)&sx[bn][2 * tid] = px;
                    if (tid >= 123) *(float2*)&sy[bn][2 * (tid - 123)] = py;
                }
                __syncthreads();
            }
        }
    }

    // reduce + one atomic per block
#pragma unroll
    for (int off = 32; off > 0; off >>= 1) tsum += __shfl_down(tsum, off, 64);
    __shared__ float wsum[4];
    const int wid = tid >> 6, lane = tid & 63;
    if (lane == 0) wsum[wid] = tsum;
    __syncthreads();
    if (tid == 0) atomicAdd(ssum, (double)(wsum[0] + wsum[1] + wsum[2] + wsum[3]));
}

// ---------------- Kernel B: L1 map + combine ----------------
// Full-width band (512 cols, 2 cols/thread), 32 output rows, 44 row iters.
// SAME zero-pad handled by 6-col zero margins in LDS + row guards.
__global__ __launch_bounds__(256) void l1_band_kernel(
        const float* __restrict__ x, const float* __restrict__ y,
        const double* __restrict__ ssum, float* __restrict__ out, KTaps kt) {
    __shared__ __align__(16) float sd[2][528];   // [0..5]=0, [6..517]=d, [518..523]=0

    const int img  = blockIdx.y;
    const int band = blockIdx.x;   // 0..15
    const int tid  = threadIdx.x;
    const int o0   = band * 32;
    const int rin0 = o0 - 6;

    const float* __restrict__ xi = x + (size_t)img * IMG_H * IMG_W;
    const float* __restrict__ yi = y + (size_t)img * IMG_H * IMG_W;
    float* __restrict__ oi = out + (size_t)img * IMG_H * IMG_W;

    const float base = 100.f * 0.84f * (1.f - (float)(*ssum) * (1.f / 16128256.f));

    float acc[13][2];
#pragma unroll
    for (int i = 0; i < 13; ++i) { acc[i][0] = 0.f; acc[i][1] = 0.f; }

    // zero the pad margins once (stay zero: stage only writes [6..517])
    if (tid < 12) {
        const int idx = (tid < 6) ? tid : (512 + tid);   // 0..5, 518..523
        sd[0][idx] = 0.f; sd[1][idx] = 0.f;
    }

    auto ldd = [&](int r) -> float2 {   // this thread's cols 2t,2t+1 of d=y-x
        float2 v = make_float2(0.f, 0.f);
        if (r >= 0 && r < IMG_H) {
            const float2 a = *(const float2*)(xi + (size_t)r * IMG_W + 2 * tid);
            const float2 bb = *(const float2*)(yi + (size_t)r * IMG_W + 2 * tid);
            v = make_float2(bb.x - a.x, bb.y - a.y);
        }
        return v;
    };

    { float2 v = ldd(rin0); *(float2*)&sd[0][6 + 2 * tid] = v; }
    __syncthreads();

#pragma unroll 1
    for (int chunk = 0; chunk < 4; ++chunk) {
#pragma unroll
        for (int p = 0; p < 13; ++p) {
            const int rr = chunk * 13 + p;
            if (rr <= 43) {
                const int b = rr & 1;
                float2 pv = make_float2(0.f, 0.f);
                const bool pre = (rr < 43);
                if (pre) pv = ldd(rin0 + rr + 1);

                // h-pass: 14-value window serves both cols (sd idx = col + j)
                float dv[14];
#pragma unroll
                for (int j = 0; j < 7; ++j) {
                    const float2 a = *(const float2*)&sd[b][2 * tid + 2 * j];
                    dv[2 * j] = a.x; dv[2 * j + 1] = a.y;
                }
                float a0 = 0.f, a1 = 0.f;
#pragma unroll
                for (int u = 0; u < 13; ++u) {
                    a0 += kt.ke[u] * dv[u];
                    a1 += kt.ke[u] * dv[u + 1];
                }
                // v-pass into mod-13 pending slots
#pragma unroll
                for (int dd = 0; dd <= 12; ++dd) {
                    const int s = (p + 13 - dd) % 13;
                    acc[s][0] += kt.ke[dd] * a0;
                    acc[s][1] += kt.ke[dd] * a1;
                }
                {
                    const int sc = (p + 1) % 13;
                    const int ro = rr - 12;
                    if (ro >= 0) {
                        const int o = o0 + ro;   // always in [0,511]
                        *(float2*)&oi[(size_t)o * IMG_W + 2 * tid] =
                            make_float2(base + 16.f * fabsf(acc[sc][0]),
                                        base + 16.f * fabsf(acc[sc][1]));
                    }
                    acc[sc][0] = 0.f; acc[sc][1] = 0.f;   // ALWAYS reset
                }
                if (pre) *(float2*)&sd[b ^ 1][6 + 2 * tid] = pv;
                __syncthreads();
            }
        }
    }
}

extern "C" void kernel_launch(void* const* d_in, const int* in_sizes, int n_in,
                              void* d_out, int out_size, void* d_ws, size_t ws_size,
                              hipStream_t stream) {
    const float* x = (const float*)d_in[0];
    const float* y = (const float*)d_in[1];
    float* out = (float*)d_out;
    double* ssum = (double*)d_ws;

    KTaps kt;
    {   // normalized gaussian win=11 sigma=1.5 (exp-based)
        double g[11], s = 0.0;
        for (int i = 0; i < 11; ++i) {
            const double d = (double)i - 5.0;
            g[i] = std::exp(-(d * d) / 4.5);
            s += g[i];
        }
        for (int i = 0; i < 11; ++i) kt.kw[i] = (float)(g[i] / s);
    }
    {   // erf-gaussian, tail=6 -> 13 taps, sigma=1.5, NOT normalized
        const double t = 0.70710678 / 1.5;
        for (int i = 0; i < 13; ++i) {
            const double xx = (double)i - 6.0;
            const double v = 0.5 * (std::erf(t * (xx + 0.5)) - std::erf(t * (xx - 0.5)));
            kt.ke[i] = (float)(v < 0.0 ? 0.0 : v);
        }
    }

    hipMemsetAsync(ssum, 0, sizeof(double), stream);

    ssim_band_kernel<<<dim3(2, 8, NIMG), dim3(256), 0, stream>>>(x, y, ssum, kt);
    l1_band_kernel<<<dim3(16, NIMG, 1), dim3(256), 0, stream>>>(x, y, ssum, out, kt);
}